// Round 5
// baseline (3629.882 us; speedup 1.0000x reference)
//
#include <hip/hip_runtime.h>
#include <cstdint>
#include <cstddef>

#define B_SZ   4
#define N_PTS  16384
#define M_CENT 2048
#define NSAMP  32
#define C_IN   64
#define H1_DIM 64
#define H2_DIM 128
#define FPS_T  512
#define PPT    (N_PTS / FPS_T)   // 32 points per thread
#define LDS_J  24                // j = 0..23 -> coords live in LDS
#define LDS_PTS (LDS_J * FPS_T)  // 12288 points, 144 KiB SoA f32
#define REG_PAIRS 4              // j = 24..31 -> 8 pts (4 v2f pairs) in registers
#define H0_STR 68                // 67 channels padded to 68 for 16B-aligned float4

typedef float v2f __attribute__((ext_vector_type(2)));

// u64 max with neighbor fetched via DPP (both 32-bit halves move from the same
// source lane; invalid lanes keep 'old' = self, i.e. identity under max).
// ~5 VALU per level at VALU latency. HW-verified (rounds 3-4 passed).
template <int CTRL>
__device__ __forceinline__ unsigned long long kmax_dpp(unsigned long long k) {
  const int lo  = (int)(unsigned)(k & 0xFFFFFFFFULL);
  const int hi  = (int)(unsigned)(k >> 32);
  const int olo = __builtin_amdgcn_update_dpp(lo, lo, CTRL, 0xF, 0xF, false);
  const int ohi = __builtin_amdgcn_update_dpp(hi, hi, CTRL, 0xF, 0xF, false);
  const unsigned long long o =
      ((unsigned long long)(unsigned)ohi << 32) | (unsigned)olo;
  return (o > k) ? o : k;
}

// ---------------------------------------------------------------------------
// K1: Farthest-point sampling. One block per batch, 512 thr x 32 pts.
// LESSON (rounds 0-4): the allocator refuses to VGPR-home large per-thread
// arrays at ANY launch_bounds (VGPR_Count 84/44/40/88 vs 64-128 state floats);
// every in-loop use of the AGPR/scratch-homed coords paid a register-file
// copy (~250 wasted VALU instr/thread/iter, active-CU VALUBusy ~74% at
// 3820 cyc/iter). Fix: remove the allocator from the critical path --
// coords for j=0..23 stream from LDS SoA (sx/sy/sz[12288], 144 KiB of the
// 160 KiB/CU; stride-1 ds_read_b32, conflict-free), only j=24..31 coords
// (24 floats) + pd (32 floats, hot -> reliably VGPR) stay in registers.
// Argmax tracks bj in [0,32) via inline-const cndmask; bi = bj*512+t once.
// Reduction: DPP u64-max (ROW_SHR 1/2/4/8 + BCAST15/31 -> lane63; cross-wave
// via LDS + ROW_SHR 1/2/4 over 8 partials -> readlane 7) -- u64 (dist,
// N-idx) key, bit-identical argmax (max dist, min idx on tie).
// Distance math: sub/mul/add/min, exact per element, numpy op order, no FMA.
// ---------------------------------------------------------------------------
__global__ __launch_bounds__(FPS_T, 2) void fps_kernel(const float* __restrict__ xyz,
                                                       float* __restrict__ out_xyz) {
#pragma clang fp contract(off)
  const int b    = blockIdx.x;
  const int t    = threadIdx.x;
  const int lane = t & 63;
  const int wave = t >> 6;           // 8 waves
  const float* bx = xyz + (size_t)b * N_PTS * 3;
  float* ox = out_xyz + (size_t)b * M_CENT * 3;

  __shared__ float sx[LDS_PTS];
  __shared__ float sy[LDS_PTS];
  __shared__ float sz[LDS_PTS];
  __shared__ unsigned long long s_key[2][8];

  // Stage points 0..12287 into LDS (SoA). Coalesced-enough; runs once.
  for (int i = t; i < LDS_PTS; i += FPS_T) {
    sx[i] = bx[i * 3 + 0];
    sy[i] = bx[i * 3 + 1];
    sz[i] = bx[i * 3 + 2];
  }

  // Points j=24..31 (global idx 12288 + (j-24)*512 + t = j*512 + t): coords
  // in registers as 4 SoA v2f pairs = 24 floats (small enough that even a
  // worst-case AGPR homing costs ~50 VALU/iter, not 250).
  v2f rx[REG_PAIRS], ry[REG_PAIRS], rz[REG_PAIRS];
#pragma unroll
  for (int r = 0; r < REG_PAIRS; ++r) {
    const int i0 = (LDS_J + 2 * r + 0) * FPS_T + t;
    const int i1 = (LDS_J + 2 * r + 1) * FPS_T + t;
    v2f vx, vy, vz;
    vx.x = bx[i0 * 3 + 0]; vx.y = bx[i1 * 3 + 0];
    vy.x = bx[i0 * 3 + 1]; vy.y = bx[i1 * 3 + 1];
    vz.x = bx[i0 * 3 + 2]; vz.y = bx[i1 * 3 + 2];
    rx[r] = vx; ry[r] = vy; rz[r] = vz;
  }
  // Init-only pin: prevents re-materializing these loads inside the m-loop.
  asm volatile("" : "+v"(rx[0]), "+v"(rx[1]), "+v"(rx[2]), "+v"(rx[3]),
                    "+v"(ry[0]), "+v"(ry[1]), "+v"(ry[2]), "+v"(ry[3]),
                    "+v"(rz[0]), "+v"(rz[1]), "+v"(rz[2]), "+v"(rz[3]));

  // Running min-distances for all 32 points (hot read-write -> VGPRs).
  v2f pdp[PPT / 2];
#pragma unroll
  for (int k = 0; k < PPT / 2; ++k) { v2f big; big.x = 1e10f; big.y = 1e10f; pdp[k] = big; }

  __syncthreads();  // LDS staging visible to all waves

  int cur = 0;  // reference idx0 = 0
  for (int m = 0; m < M_CENT; ++m) {
    const int curs = __builtin_amdgcn_readfirstlane(cur);  // uniform -> SGPR path
    const float cx = bx[curs * 3 + 0];                     // L2-hot broadcast
    const float cy = bx[curs * 3 + 1];
    const float cz = bx[curs * 3 + 2];
    if (t == 0) { ox[m * 3 + 0] = cx; ox[m * 3 + 1] = cy; ox[m * 3 + 2] = cz; }
    if (m == M_CENT - 1) break;

    v2f vcx, vcy, vcz;
    vcx.x = cx; vcx.y = cx;
    vcy.x = cy; vcy.y = cy;
    vcz.x = cz; vcz.y = cz;
    float bv = -1.0f;  // dists >= 0, so first point always taken
    int   bj = 0;      // best j in [0,32); global idx = bj*512 + t

    // --- LDS-resident points: pairs (2jp, 2jp+1), jp = 0..11 ---
#pragma unroll
    for (int jp = 0; jp < LDS_J / 2; ++jp) {
      const int i0 = (2 * jp) * FPS_T + t;   // LDS index; i1 = i0 + FPS_T
      v2f xx, yy, zz;
      xx.x = sx[i0]; xx.y = sx[i0 + FPS_T];
      yy.x = sy[i0]; yy.y = sy[i0 + FPS_T];
      zz.x = sz[i0]; zz.y = sz[i0 + FPS_T];
      const v2f dx = xx - vcx;
      const v2f dy = yy - vcy;
      const v2f dz = zz - vcz;
      const v2f sxq = dx * dx;
      const v2f syq = dy * dy;
      const v2f szq = dz * dz;
      const v2f s1  = sxq + syq;
      const v2f d2  = s1 + szq;             // (dx2+dy2)+dz2, numpy order, no FMA
      v2f nd = pdp[jp];
      nd.x = fminf(nd.x, d2.x);
      nd.y = fminf(nd.y, d2.y);
      pdp[jp] = nd;
      const bool c0 = nd.x > bv;            // strict >: min global idx on tie
      bv = c0 ? nd.x : bv;
      bj = c0 ? (2 * jp + 0) : bj;          // inline-const cndmask
      const bool c1 = nd.y > bv;
      bv = c1 ? nd.y : bv;
      bj = c1 ? (2 * jp + 1) : bj;
    }
    // --- register-resident points: pairs j = (24+2r, 25+2r), r = 0..3 ---
#pragma unroll
    for (int r = 0; r < REG_PAIRS; ++r) {
      const v2f dx = rx[r] - vcx;
      const v2f dy = ry[r] - vcy;
      const v2f dz = rz[r] - vcz;
      const v2f sxq = dx * dx;
      const v2f syq = dy * dy;
      const v2f szq = dz * dz;
      const v2f s1  = sxq + syq;
      const v2f d2  = s1 + szq;
      v2f nd = pdp[LDS_J / 2 + r];
      nd.x = fminf(nd.x, d2.x);
      nd.y = fminf(nd.y, d2.y);
      pdp[LDS_J / 2 + r] = nd;
      const bool c0 = nd.x > bv;
      bv = c0 ? nd.x : bv;
      bj = c0 ? (LDS_J + 2 * r + 0) : bj;
      const bool c1 = nd.y > bv;
      bv = c1 ? nd.y : bv;
      bj = c1 ? (LDS_J + 2 * r + 1) : bj;
    }

    const int bi = bj * FPS_T + t;
    // pack: high = float bits (>=0, monotone), low = N-idx so ties -> min idx
    unsigned long long key = ((unsigned long long)__float_as_uint(bv) << 32)
                           | (unsigned int)(N_PTS - bi);
    // intra-wave max -> lane 63 (other lanes hold partial maxes; only 63 used)
    key = kmax_dpp<0x111>(key);   // row_shr:1
    key = kmax_dpp<0x112>(key);   // row_shr:2
    key = kmax_dpp<0x114>(key);   // row_shr:4
    key = kmax_dpp<0x118>(key);   // row_shr:8
    key = kmax_dpp<0x142>(key);   // row_bcast15
    key = kmax_dpp<0x143>(key);   // row_bcast31
    const int p = m & 1;
    if (lane == 63) s_key[p][wave] = key;
    __syncthreads();
    // all waves redundantly reduce the 8 per-wave keys (no 2nd barrier):
    // each 16-lane row loads the 8 partials, ROW_SHR tree -> lane 7.
    unsigned long long k2 = s_key[p][lane & 7];
    k2 = kmax_dpp<0x111>(k2);
    k2 = kmax_dpp<0x112>(k2);
    k2 = kmax_dpp<0x114>(k2);
    const int lo7 = __builtin_amdgcn_readlane((int)(unsigned)(k2 & 0xFFFFFFFFULL), 7);
    cur = N_PTS - lo7;
  }
}

// ---------------------------------------------------------------------------
// K2: Ball query. One wave per centroid: ballot + prefix popcount appends the
// first 32 in-radius indices in index order (== top_k(-order) semantics),
// pads with the first hit. Early exit once 32 found.
// ---------------------------------------------------------------------------
__global__ __launch_bounds__(256) void ballq_kernel(const float* __restrict__ xyz,
                                                    const float* __restrict__ new_xyz,
                                                    int* __restrict__ idx_out) {
#pragma clang fp contract(off)
  const int lane = threadIdx.x & 63;
  const int gid  = blockIdx.x * 4 + (threadIdx.x >> 6);
  if (gid >= B_SZ * M_CENT) return;
  const int b = gid >> 11;  // / M_CENT
  const float* bx = xyz + (size_t)b * N_PTS * 3;
  const float cx = new_xyz[gid * 3 + 0];
  const float cy = new_xyz[gid * 3 + 1];
  const float cz = new_xyz[gid * 3 + 2];
  const float rr = (float)(0.8 * 0.8);  // double 0.64 -> f32 (JAX weak-scalar cast)
  int* out = idx_out + (size_t)gid * NSAMP;

  int count = 0;
  int first = -1;
  for (int base = 0; base < N_PTS; base += 64) {
    const int i = base + lane;
    const float dx = bx[i * 3 + 0] - cx;
    const float dy = bx[i * 3 + 1] - cy;
    const float dz = bx[i * 3 + 2] - cz;
    const float d = (dx * dx + dy * dy) + dz * dz;
    const bool pred = d < rr;
    const unsigned long long mk = __ballot(pred);
    if (pred) {
      const int slot = count + __popcll(mk & ((1ULL << lane) - 1ULL));
      if (slot < NSAMP) out[slot] = i;
    }
    if (first < 0 && mk != 0ULL) first = base + (__ffsll((long long)mk) - 1);
    count += __popcll(mk);
    if (count >= NSAMP) break;
  }
  if (count < NSAMP) {
    for (int k = count + lane; k < NSAMP; k += 64) out[k] = first;  // centroid itself is a hit
  }
}

// ---------------------------------------------------------------------------
// K3: gather + MLP(67->64 relu, 64->128 relu) + max over 32 samples.
// One 128-thread block per centroid. h0/h1 staged in LDS; reads are
// wave-uniform float4 broadcasts; weights coalesced from L1/L2.
// ---------------------------------------------------------------------------
__global__ __launch_bounds__(128) void mlp_kernel(const float* __restrict__ xyz,
                                                  const float* __restrict__ feats,
                                                  const float* __restrict__ new_xyz,
                                                  const int* __restrict__ idx,
                                                  const float* __restrict__ w1,
                                                  const float* __restrict__ b1,
                                                  const float* __restrict__ w2,
                                                  const float* __restrict__ b2,
                                                  float* __restrict__ out_feats) {
  const int gid = blockIdx.x;
  const int t   = threadIdx.x;
  const int b   = gid >> 11;  // / M_CENT

  __shared__ float h0[NSAMP * H0_STR];
  __shared__ float h1[NSAMP * H1_DIM];
  __shared__ int   sidx[NSAMP];

  if (t < NSAMP) sidx[t] = idx[(size_t)gid * NSAMP + t];
  const float cx = new_xyz[gid * 3 + 0];
  const float cy = new_xyz[gid * 3 + 1];
  const float cz = new_xyz[gid * 3 + 2];
  __syncthreads();

  const float* bxyz = xyz + (size_t)b * N_PTS * 3;
  const float* bft  = feats + (size_t)b * N_PTS * C_IN;
  for (int e = t; e < NSAMP * 67; e += 128) {
    const int s = e / 67;
    const int c = e - s * 67;
    const int p = sidx[s];
    float v;
    if (c < 3) {
      const float pc = bxyz[p * 3 + c];
      v = pc - (c == 0 ? cx : (c == 1 ? cy : cz));
    } else {
      v = bft[(size_t)p * C_IN + (c - 3)];
    }
    h0[s * H0_STR + c] = v;
  }
  __syncthreads();

  // layer 1: col = t&63 over H1_DIM, half = t>>6 picks 16 of 32 samples
  {
    const int col  = t & 63;
    const int half = t >> 6;
    float acc[16];
    const float bb = b1[col];
#pragma unroll
    for (int s = 0; s < 16; ++s) acc[s] = bb;
    const float* h0base = h0 + (half * 16) * H0_STR;
    for (int k = 0; k < 64; k += 4) {
      const float w0v = w1[(k + 0) * H1_DIM + col];
      const float w1v = w1[(k + 1) * H1_DIM + col];
      const float w2v = w1[(k + 2) * H1_DIM + col];
      const float w3v = w1[(k + 3) * H1_DIM + col];
#pragma unroll
      for (int s = 0; s < 16; ++s) {
        const float4 h4 = *reinterpret_cast<const float4*>(h0base + s * H0_STR + k);
        acc[s] += h4.x * w0v + h4.y * w1v + h4.z * w2v + h4.w * w3v;
      }
    }
    for (int k = 64; k < 67; ++k) {
      const float wv = w1[k * H1_DIM + col];
#pragma unroll
      for (int s = 0; s < 16; ++s) acc[s] += h0base[s * H0_STR + k] * wv;
    }
#pragma unroll
    for (int s = 0; s < 16; ++s) h1[(half * 16 + s) * H1_DIM + col] = fmaxf(acc[s], 0.0f);
  }
  __syncthreads();

  // layer 2 + max-pool: col = t over H2_DIM
  {
    float acc[32];
    const float bb = b2[t];
#pragma unroll
    for (int s = 0; s < 32; ++s) acc[s] = bb;
    for (int k = 0; k < 64; k += 4) {
      const float w0v = w2[(k + 0) * H2_DIM + t];
      const float w1v = w2[(k + 1) * H2_DIM + t];
      const float w2v = w2[(k + 2) * H2_DIM + t];
      const float w3v = w2[(k + 3) * H2_DIM + t];
#pragma unroll
      for (int s = 0; s < 32; ++s) {
        const float4 h4 = *reinterpret_cast<const float4*>(&h1[s * H1_DIM + k]);
        acc[s] += h4.x * w0v + h4.y * w1v + h4.z * w2v + h4.w * w3v;
      }
    }
    float mx = 0.0f;  // max(relu(v)) == max(0, max(v))
#pragma unroll
    for (int s = 0; s < 32; ++s) mx = fmaxf(mx, acc[s]);
    out_feats[(size_t)gid * H2_DIM + t] = mx;
  }
}

// ---------------------------------------------------------------------------
extern "C" void kernel_launch(void* const* d_in, const int* in_sizes, int n_in,
                              void* d_out, int out_size, void* d_ws, size_t ws_size,
                              hipStream_t stream) {
  const float* xyz   = (const float*)d_in[0];  // (4,16384,3) f32
  const float* feats = (const float*)d_in[1];  // (4,16384,64) f32
  // d_in[2] = bid (unused; output bid is all zeros)
  const float* w1 = (const float*)d_in[3];     // (67,64)
  const float* b1 = (const float*)d_in[4];     // (64,)
  const float* w2 = (const float*)d_in[5];     // (64,128)
  const float* b2 = (const float*)d_in[6];     // (128,)

  float* out       = (float*)d_out;
  float* out_xyz   = out;                                        // (4,2048,3)
  float* out_feats = out + (size_t)B_SZ * M_CENT * 3;            // (4,2048,128)
  float* out_bid   = out_feats + (size_t)B_SZ * M_CENT * H2_DIM; // (4,2048,1) int32 zeros
  int*   idx_ws    = (int*)d_ws;                                 // (4,2048,32) int32, 1 MiB

  hipLaunchKernelGGL(fps_kernel, dim3(B_SZ), dim3(FPS_T), 0, stream, xyz, out_xyz);
  hipLaunchKernelGGL(ballq_kernel, dim3((B_SZ * M_CENT + 3) / 4), dim3(256), 0, stream,
                     xyz, out_xyz, idx_ws);
  hipLaunchKernelGGL(mlp_kernel, dim3(B_SZ * M_CENT), dim3(128), 0, stream,
                     xyz, feats, out_xyz, idx_ws, w1, b1, w2, b2, out_feats);
  hipMemsetAsync(out_bid, 0, (size_t)B_SZ * M_CENT * sizeof(int), stream);
}